// Round 5
// baseline (41.604 us; speedup 1.0000x reference)
//
#include <hip/hip_runtime.h>

// Post_process_deconv: out = depth + b + sum_k w[k] * (weight[k] - mean_k(weight)) *
//                           bilinear(depth, y - 1 + kh + dy_k, x - 1 + kw + dx_k)
// Shapes: depth [B,1,H,W], weight [B,9,H,W], offset [B,18,H,W], w [1,1,3,3], b [1]
// B=2, H=352, W=1216, K=3, pad=1. All fp32.
//
// Round 5: gather-count is the proven lever (36->18 gave 1.35x). Go 18->9:
// precompute Dp[y][x] = (depth[y][x], depth[y+1][x]) as float2 in d_ws, so ONE
// 16B gather per tap yields all 4 bilinear corners (v00,v10,v01,v11); clamp /
// zero-outside cases resolved with cndmasks. Streaming weight/offset loads and
// the out store are nontemporal so the 32KB L1 keeps the Dp gather working set
// (~26KB/block) resident. Fallback to the round-4 kernel if ws too small.

#define KK 3
#define K2 9
#define PAD 1
#define BB 2
#define HH 352
#define WW 1216

// ---------------- pack kernel: Dp[b][y][x] = (d[y][x], d[y+1 clamped][x]) --------
__global__ __launch_bounds__(256) void pack_kernel(
    const float* __restrict__ depth, float2* __restrict__ dp)
{
    constexpr int HW = HH * WW;
    constexpr int total = BB * HW;
    const int idx = blockIdx.x * blockDim.x + threadIdx.x;
    if (idx >= total) return;
    const int b  = idx / HW;
    const int hw = idx - b * HW;
    const int y  = hw / WW;
    const float a = depth[idx];
    const float c = depth[idx + ((y < HH - 1) ? WW : 0)];
    dp[idx] = make_float2(a, c);
}

// ---------------- main kernel (packed gathers) ----------------
__global__ __launch_bounds__(256) void ppd_kernel(
    const float* __restrict__ depth,   // [B, H*W]
    const float2* __restrict__ dp,     // [B, H*W] packed row pairs
    const float* __restrict__ weight,  // [B, 9, H*W]
    const float* __restrict__ offset,  // [B, 18, H*W]
    const float* __restrict__ wk,      // [9]
    const float* __restrict__ bias,    // [1]
    float* __restrict__ out)           // [B, H*W]
{
    constexpr int HW = HH * WW;
    constexpr int total = BB * HW;
    const int idx = blockIdx.x * blockDim.x + threadIdx.x;
    if (idx >= total) return;

    const int b  = idx / HW;
    const int hw = idx - b * HW;
    const int y  = hw / WW;
    const int x  = hw - y * WW;

    const float2* dpb = dp     + (size_t)b * HW;
    const float*  wgt = weight + (size_t)b * (K2 * HW) + hw;
    const float*  off = offset + (size_t)b * (2 * K2 * HW) + hw;

    // Streaming plane loads — nontemporal so they don't evict Dp from L1.
    float wv[K2], dyv[K2], dxv[K2];
#pragma unroll
    for (int k = 0; k < K2; ++k) wv[k] = __builtin_nontemporal_load(&wgt[k * HW]);
#pragma unroll
    for (int k = 0; k < K2; ++k) {
        dyv[k] = __builtin_nontemporal_load(&off[(2 * k)     * HW]);
        dxv[k] = __builtin_nontemporal_load(&off[(2 * k + 1) * HW]);
    }
    const float dres = __builtin_nontemporal_load(&depth[idx]);   // residual

    float wsum = 0.f;
#pragma unroll
    for (int k = 0; k < K2; ++k) wsum += wv[k];
    const float wmean = wsum * (1.0f / 9.0f);

    float acc = 0.f;
#pragma unroll
    for (int k = 0; k < K2; ++k) {
        const int kh = k / KK;
        const int kw = k - kh * KK;
        const float py = (float)(y - PAD + kh) + dyv[k];
        const float px = (float)(x - PAD + kw) + dxv[k];

        const float y0f = floorf(py);
        const float x0f = floorf(px);
        const float ly = py - y0f;
        const float lx = px - x0f;
        const int y0 = (int)y0f;
        const int x0 = (int)x0f;

        // validity folded into bilinear weights (zero-outside semantics)
        const float wy0 = ((unsigned)y0       < (unsigned)HH) ? (1.f - ly) : 0.f;
        const float wy1 = ((unsigned)(y0 + 1) < (unsigned)HH) ? ly         : 0.f;
        const float wx0 = ((unsigned)x0       < (unsigned)WW) ? (1.f - lx) : 0.f;
        const float wx1 = ((unsigned)(x0 + 1) < (unsigned)WW) ? lx         : 0.f;

        const int r  = min(max(y0, 0), HH - 1);
        const int xb = min(max(x0, 0), WW - 2);

        // ONE 16B gather: (d[r][xb], d[r+1][xb], d[r][xb+1], d[r+1][xb+1])
        float4 q;
        __builtin_memcpy(&q, dpb + (size_t)r * WW + xb, 16);

        // Row-1 fixup: if y0 < 0 (r clamped up), the "next row" value for the
        // y1=0 row is the .x element (row 0), not .y.
        const bool yok = (y0 >= 0);
        const float r1a = yok ? q.y : q.x;
        const float r1b = yok ? q.w : q.z;

        // Column selects (xb clamping): lo0 <=> x0c==xb ; lo1 <=> x1c==xb.
        const bool lo0 = (x0 < WW - 1);
        const bool lo1 = (x0 < 0);
        const float v00 = lo0 ? q.x : q.z;
        const float v01 = lo1 ? q.x : q.z;
        const float v10 = lo0 ? r1a : r1b;
        const float v11 = lo1 ? r1a : r1b;

        const float s = wy0 * (wx0 * v00 + wx1 * v01)
                      + wy1 * (wx0 * v10 + wx1 * v11);

        acc = fmaf(wk[k] * (wv[k] - wmean), s, acc);
    }

    __builtin_nontemporal_store(acc + bias[0] + dres, &out[idx]);
}

// ---------------- fallback (round-4 kernel, no workspace) ----------------
__global__ __launch_bounds__(256) void ppd_kernel_nows(
    const float* __restrict__ depth,
    const float* __restrict__ weight,
    const float* __restrict__ offset,
    const float* __restrict__ wk,
    const float* __restrict__ bias,
    float* __restrict__ out)
{
    constexpr int HW = HH * WW;
    constexpr int total = BB * HW;
    const int idx = blockIdx.x * blockDim.x + threadIdx.x;
    if (idx >= total) return;

    const int b  = idx / HW;
    const int hw = idx - b * HW;
    const int y  = hw / WW;
    const int x  = hw - y * WW;

    const float* dimg = depth  + (size_t)b * HW;
    const float* wgt  = weight + (size_t)b * (K2 * HW) + hw;
    const float* off  = offset + (size_t)b * (2 * K2 * HW) + hw;

    float wv[K2], dyv[K2], dxv[K2];
#pragma unroll
    for (int k = 0; k < K2; ++k) wv[k] = wgt[k * HW];
#pragma unroll
    for (int k = 0; k < K2; ++k) {
        dyv[k] = off[(2 * k)     * HW];
        dxv[k] = off[(2 * k + 1) * HW];
    }
    const float dres = dimg[hw];

    float wsum = 0.f;
#pragma unroll
    for (int k = 0; k < K2; ++k) wsum += wv[k];
    const float wmean = wsum * (1.0f / 9.0f);

    float acc = 0.f;
#pragma unroll
    for (int k = 0; k < K2; ++k) {
        const int kh = k / KK;
        const int kw = k - kh * KK;
        const float py = (float)(y - PAD + kh) + dyv[k];
        const float px = (float)(x - PAD + kw) + dxv[k];

        const float y0f = floorf(py);
        const float x0f = floorf(px);
        const float ly = py - y0f;
        const float lx = px - x0f;
        const int y0 = (int)y0f;
        const int x0 = (int)x0f;

        const float wy0 = ((unsigned)y0       < (unsigned)HH) ? (1.f - ly) : 0.f;
        const float wy1 = ((unsigned)(y0 + 1) < (unsigned)HH) ? ly         : 0.f;
        const float wx0 = ((unsigned)x0       < (unsigned)WW) ? (1.f - lx) : 0.f;
        const float wx1 = ((unsigned)(x0 + 1) < (unsigned)WW) ? lx         : 0.f;

        const int y0c = min(max(y0, 0), HH - 1);
        const int y1c = min(max(y0 + 1, 0), HH - 1);
        const int xb  = min(max(x0, 0), WW - 2);
        const int x0c = min(max(x0, 0), WW - 1);
        const int x1c = min(max(x0 + 1, 0), WW - 1);

        const float* r0 = dimg + y0c * WW + xb;
        const float* r1 = dimg + y1c * WW + xb;
        float2 p0, p1;
        __builtin_memcpy(&p0, r0, 8);
        __builtin_memcpy(&p1, r1, 8);

        const bool lo0 = (x0c == xb);
        const bool lo1 = (x1c == xb);
        const float v00 = lo0 ? p0.x : p0.y;
        const float v01 = lo1 ? p0.x : p0.y;
        const float v10 = lo0 ? p1.x : p1.y;
        const float v11 = lo1 ? p1.x : p1.y;

        const float s = wy0 * (wx0 * v00 + wx1 * v01)
                      + wy1 * (wx0 * v10 + wx1 * v11);

        acc = fmaf(wk[k] * (wv[k] - wmean), s, acc);
    }

    out[idx] = acc + bias[0] + dres;
}

extern "C" void kernel_launch(void* const* d_in, const int* in_sizes, int n_in,
                              void* d_out, int out_size, void* d_ws, size_t ws_size,
                              hipStream_t stream) {
    const float* depth  = (const float*)d_in[0];
    const float* weight = (const float*)d_in[1];
    const float* offset = (const float*)d_in[2];
    const float* wk     = (const float*)d_in[3];
    const float* bias   = (const float*)d_in[4];
    float* out = (float*)d_out;

    constexpr int total = BB * HH * WW;
    constexpr size_t dp_bytes = (size_t)total * sizeof(float2);
    const int block = 256;
    const int grid = (total + block - 1) / block;

    if (ws_size >= dp_bytes) {
        float2* dp = (float2*)d_ws;
        pack_kernel<<<grid, block, 0, stream>>>(depth, dp);
        ppd_kernel<<<grid, block, 0, stream>>>(depth, dp, weight, offset, wk, bias, out);
    } else {
        ppd_kernel_nows<<<grid, block, 0, stream>>>(depth, weight, offset, wk, bias, out);
    }
}

// Round 6
// 25.077 us; speedup vs baseline: 1.6591x; 1.6591x over previous
//
#include <hip/hip_runtime.h>

// Post_process_deconv: out = depth + b + sum_k w[k] * (weight[k] - mean_k(weight)) *
//                           bilinear(depth, y - 1 + kh + dy_k, x - 1 + kw + dx_k)
// Shapes: depth [B,1,H,W], weight [B,9,H,W], offset [B,18,H,W], w [1,1,3,3], b [1]
// B=2, H=352, W=1216, K=3, pad=1. All fp32.
//
// Round 6: gathers moved OFF the vector-memory pipe. Each block owns a 64x4
// pixel tile and stages depth rows [y-7, y+11] x cols [x-7, x+72] (19x80 fp32
// = 6.1 KB) into LDS, zero-filled outside the image (so zero-outside semantics
// are free and the fast path uses raw bilinear weights). All 36 corner reads
// per pixel come from LDS (own pipe, ~free conflicts at random addrs). Taps
// falling outside the +-6 halo (P ~ 2e-9 per tap for N(0,1) offsets) take a
// divergent global-clamped fallback branch -- correctness never depends on
// the offset distribution; the branch is s_cbranch_execz-skipped otherwise.

#define KK 3
#define K2 9
#define PAD 1
#define BB 2
#define HH 352
#define WW 1216

#define TX 64          // tile width  (19 tiles:  19*64 = 1216)
#define TY 4           // tile height (88 tiles:  88*4  = 352)
#define NTX (WW / TX)
#define NTY (HH / TY)
#define HALO 7
#define SROWS (TY + 2 * HALO + 1)   // 19
#define SCOLS (TX + 2 * HALO + 2)   // 80

__global__ __launch_bounds__(256) void ppd_kernel(
    const float* __restrict__ depth,   // [B, H*W]
    const float* __restrict__ weight,  // [B, 9, H*W]
    const float* __restrict__ offset,  // [B, 18, H*W]
    const float* __restrict__ wk,      // [9]
    const float* __restrict__ bias,    // [1]
    float* __restrict__ out)           // [B, H*W]
{
    constexpr int HW = HH * WW;

    __shared__ float sd[SROWS * SCOLS];   // 6080 B

    const int bid = blockIdx.x;
    const int b   = bid / (NTY * NTX);
    const int rem = bid - b * (NTY * NTX);
    const int ty  = rem / NTX;
    const int tx  = rem - ty * NTX;

    const int tid = threadIdx.x;
    const int lx  = tid & (TX - 1);
    const int lyq = tid >> 6;             // 0..3
    const int x   = tx * TX + lx;
    const int y   = ty * TY + lyq;

    const float* dimg = depth + (size_t)b * HW;
    const int base_y = ty * TY - HALO;
    const int base_x = tx * TX - HALO;

    // ---- stage depth tile into LDS (zero-filled outside image) ----
    for (int t = tid; t < SROWS * SCOLS; t += 256) {
        const int r  = t / SCOLS;
        const int c  = t - r * SCOLS;
        const int gy = base_y + r;
        const int gx = base_x + c;
        float v = 0.f;
        if ((unsigned)gy < (unsigned)HH && (unsigned)gx < (unsigned)WW)
            v = dimg[gy * WW + gx];
        sd[t] = v;
    }

    // ---- streaming plane loads (coalesced; issue while LDS fills) ----
    const int hw = y * WW + x;
    const float* wgt = weight + (size_t)b * (K2 * HW) + hw;
    const float* off = offset + (size_t)b * (2 * K2 * HW) + hw;

    float wv[K2], dyv[K2], dxv[K2];
#pragma unroll
    for (int k = 0; k < K2; ++k) wv[k] = wgt[k * HW];
#pragma unroll
    for (int k = 0; k < K2; ++k) {
        dyv[k] = off[(2 * k)     * HW];
        dxv[k] = off[(2 * k + 1) * HW];
    }
    const float dres = dimg[hw];

    float wsum = 0.f;
#pragma unroll
    for (int k = 0; k < K2; ++k) wsum += wv[k];
    const float wmean = wsum * (1.0f / 9.0f);

    __syncthreads();

    float acc = 0.f;
#pragma unroll
    for (int k = 0; k < K2; ++k) {
        const int kh = k / KK;
        const int kw = k - kh * KK;
        const float py = (float)(y - PAD + kh) + dyv[k];
        const float px = (float)(x - PAD + kw) + dxv[k];

        const float y0f = floorf(py);
        const float x0f = floorf(px);
        const float fy = py - y0f;        // ly
        const float fx = px - x0f;        // lx
        const int y0 = (int)y0f;
        const int x0 = (int)x0f;

        const int lr = y0 - base_y;       // want [0, SROWS-2]
        const int lc = x0 - base_x;       // want [0, SCOLS-2]

        float s;
        if (__builtin_expect((unsigned)lr <= (unsigned)(SROWS - 2) &&
                             (unsigned)lc <= (unsigned)(SCOLS - 2), 1)) {
            // fast path: all 4 corners from LDS; OOB already zero-filled,
            // so raw bilinear weights are correct.
            const float* r0 = &sd[lr * SCOLS + lc];
            const float v00 = r0[0];
            const float v01 = r0[1];
            const float v10 = r0[SCOLS];
            const float v11 = r0[SCOLS + 1];
            s = (1.f - fy) * ((1.f - fx) * v00 + fx * v01)
              + fy         * ((1.f - fx) * v10 + fx * v11);
        } else {
            // rare fallback: global clamped loads + validity-folded weights
            const float wy0 = ((unsigned)y0       < (unsigned)HH) ? (1.f - fy) : 0.f;
            const float wy1 = ((unsigned)(y0 + 1) < (unsigned)HH) ? fy         : 0.f;
            const float wx0 = ((unsigned)x0       < (unsigned)WW) ? (1.f - fx) : 0.f;
            const float wx1 = ((unsigned)(x0 + 1) < (unsigned)WW) ? fx         : 0.f;
            const int y0c = min(max(y0, 0), HH - 1);
            const int y1c = min(max(y0 + 1, 0), HH - 1);
            const int x0c = min(max(x0, 0), WW - 1);
            const int x1c = min(max(x0 + 1, 0), WW - 1);
            const float v00 = dimg[y0c * WW + x0c];
            const float v01 = dimg[y0c * WW + x1c];
            const float v10 = dimg[y1c * WW + x0c];
            const float v11 = dimg[y1c * WW + x1c];
            s = wy0 * (wx0 * v00 + wx1 * v01)
              + wy1 * (wx0 * v10 + wx1 * v11);
        }

        acc = fmaf(wk[k] * (wv[k] - wmean), s, acc);
    }

    out[(size_t)b * HW + hw] = acc + bias[0] + dres;
}

extern "C" void kernel_launch(void* const* d_in, const int* in_sizes, int n_in,
                              void* d_out, int out_size, void* d_ws, size_t ws_size,
                              hipStream_t stream) {
    const float* depth  = (const float*)d_in[0];
    const float* weight = (const float*)d_in[1];
    const float* offset = (const float*)d_in[2];
    const float* wk     = (const float*)d_in[3];
    const float* bias   = (const float*)d_in[4];
    float* out = (float*)d_out;

    const int grid = BB * NTY * NTX;   // 3344
    ppd_kernel<<<grid, 256, 0, stream>>>(depth, weight, offset, wk, bias, out);
}